// Round 10
// baseline (97.708 us; speedup 1.0000x reference)
//
#include <hip/hip_runtime.h>

// B=32, C=16, RES=128, NA=64
// out[b,0,a,i] = bias + sum_j bilinear(y[b],...), y[b] = sum_c w[c]*x[b,c]
//
// LDS element E[r][c] = (b0[r,c], b1[r,c]) as 2 x fp16 (4 B), 2-px zero guard,
// stride 133. 73.7 KB LDS -> 2 blocks/CU; j-range split in two -> 512 blocks,
// 4 waves/SIMD (R7 concept, minus its spill: bounds (512,2) caps VGPR at 128,
// fp32 accumulation, no deep fp16 pipeline). Taps: two ds_read2_b32
// ({0,1},{133,134}); interp: 8 x v_fma_mix_f32 (fp16 taps, fp32 acc).
// Halves combined by f32 atomicAdd into memset-zeroed out.

#define B_    32
#define C_    16
#define RES   128
#define NA    64
#define SLDS  133              // row stride in 4-B elements (read2 offset1 <= 255)
#define ROWS  132
#define NELEM (ROWS * SLDS)    // 17556 elements
#define NPADE 18432            // padded: 18432*4 B = 73728 B = 512 thr * 9 uint4
#define NPAIR 16

typedef _Float16 half2v __attribute__((ext_vector_type(2)));

// ---------------- Kernel 1: fused channel-reduce + guarded pair-pack ----------------
// grid = 16 pairs x 128 rows, 256 threads; t: u = t>>7 (batch), m = t&127 (col)
__global__ __launch_bounds__(256) void chanpack(const float* __restrict__ x,
                                                const float* __restrict__ w,
                                                unsigned int* __restrict__ pk) {
    const int blk = blockIdx.x;
    const int p   = blk >> 7;          // pair
    const int q   = blk & 127;         // image row
    const int t   = threadIdx.x;
    const int u   = t >> 7;            // batch within pair
    const int m   = t & 127;           // column

    __shared__ float rowbuf[2][128];

    float wr[C_];
#pragma unroll
    for (int c = 0; c < C_; ++c) wr[c] = w[c];

    const float* xb = x + ((size_t)(2 * p + u) * C_) * (RES * RES) + q * RES + m;
    float acc = 0.f;
#pragma unroll
    for (int c = 0; c < C_; ++c) acc = fmaf(wr[c], xb[c * (RES * RES)], acc);

    rowbuf[u][m] = acc;
    __syncthreads();

    // packed row r = q+2 (133 elements); pixel col m lives at element m+2
    unsigned int* dst = pk + (size_t)p * NPADE + (q + 2) * SLDS;
    if (t < SLDS) {
        int c = t;
        unsigned int v = 0u;
        if (c >= 2 && c <= 129)
            v = __builtin_bit_cast(unsigned int,
                    __builtin_amdgcn_cvt_pkrtz(rowbuf[0][c - 2], rowbuf[1][c - 2]));
        dst[c] = v;
    }

    // q==0 blocks zero the guard rows (0,1,130,131) and the pad tail
    if (q == 0) {
        unsigned int* base = pk + (size_t)p * NPADE;
        for (int k = t; k < 2 * SLDS; k += 256) {
            base[k] = 0u;                       // rows 0,1
            base[130 * SLDS + k] = 0u;          // rows 130,131
        }
        for (int k = t; k < NPADE - NELEM; k += 256)
            base[NELEM + k] = 0u;               // pad tail
    }
}

// ---------------- Kernel 2: radon, 2 batches/block, half j-range ----------------
// grid = 16 pairs x 16 grp x 2 jhalf = 512 blocks, 512 thr -> 2 blocks/CU
__global__ __launch_bounds__(512, 2) void radon_k(const unsigned int* __restrict__ pk,
                                                  const float* __restrict__ angles,
                                                  const float* __restrict__ bias,
                                                  float* __restrict__ out) {
    __shared__ unsigned int lds[NPADE];   // 73728 B -> 2 blocks/CU
    const int bid = blockIdx.x;
    const int h   = bid & 1;              // j-half
    const int grp = (bid >> 1) & 15;
    const int p   = bid >> 5;
    const int t   = threadIdx.x;

    // ---- branch-free bulk stage: 9 uint4 per thread ----
    {
        const uint4* src = (const uint4*)(pk + (size_t)p * NPADE);
        uint4*       dst = (uint4*)lds;
#pragma unroll
        for (int k = 0; k < 9; ++k) dst[k * 512 + t] = src[k * 512 + t];
    }
    __syncthreads();

    const int a = (t >> 7) * 16 + grp;    // wave-uniform angle (interleaved)
    const int i = t & 127;
    float th = angles[a];
    float s, c;
    __sincosf(th, &s, &c);

    const float ci = (float)i - 63.5f;
    const float j0 = (float)(h * 64);
    // X(j0+jf) = Xb + jf*(-s);  Y(j0+jf) = Yb + jf*c   (+2 guard offset)
    const float Xb = fmaf(ci, c, fmaf(63.5f - j0, s, 65.5f));
    const float Yb = fmaf(ci, s, fmaf(j0 - 63.5f, c, 65.5f));
    const float ns = -s;

    float acc0 = 0.f, acc1 = 0.f;
#pragma unroll 8
    for (int j = 0; j < 64; ++j) {
        float jf = (float)j;
        float X  = fmaf(jf, ns, Xb);
        float Y  = fmaf(jf, c,  Yb);
        float fx = floorf(X), fy = floorf(Y);
        float wx = X - fx,    wy = Y - fy;
        float gx = fminf(fmaxf(fx, 0.f), 130.f);    // v_med3_f32
        float gy = fminf(fmaxf(fy, 0.f), 130.f);
        int addr = (int)fmaf(gy, (float)SLDS, gx);  // exact (< 2^24)
        half2v q00 = __builtin_bit_cast(half2v, lds[addr]);
        half2v q01 = __builtin_bit_cast(half2v, lds[addr + 1]);        // ds_read2_b32
        half2v q10 = __builtin_bit_cast(half2v, lds[addr + SLDS]);
        half2v q11 = __builtin_bit_cast(half2v, lds[addr + SLDS + 1]); // ds_read2_b32
        float un = 1.f - wx;
        float A0 = 1.f - wy;
        float w00 = A0 * un, w01 = A0 * wx, w10 = wy * un, w11 = wy * wx;
        acc0 = fmaf((float)q00.x, w00, acc0);   // v_fma_mix_f32
        acc1 = fmaf((float)q00.y, w00, acc1);
        acc0 = fmaf((float)q01.x, w01, acc0);
        acc1 = fmaf((float)q01.y, w01, acc1);
        acc0 = fmaf((float)q10.x, w10, acc0);
        acc1 = fmaf((float)q10.y, w10, acc1);
        acc0 = fmaf((float)q11.x, w11, acc0);
        acc1 = fmaf((float)q11.y, w11, acc1);
    }

    float bv = (h == 0) ? bias[0] : 0.f;
    atomicAdd(&out[(2 * p)     * (NA * RES) + a * RES + i], acc0 + bv);
    atomicAdd(&out[(2 * p + 1) * (NA * RES) + a * RES + i], acc1 + bv);
}

extern "C" void kernel_launch(void* const* d_in, const int* in_sizes, int n_in,
                              void* d_out, int out_size, void* d_ws, size_t ws_size,
                              hipStream_t stream) {
    const float* x      = (const float*)d_in[0];   // 32*16*128*128
    const float* angles = (const float*)d_in[1];   // 64
    const float* w      = (const float*)d_in[2];   // 16
    const float* bias   = (const float*)d_in[3];   // 1
    float* out = (float*)d_out;                    // 32*64*128 fp32

    unsigned int* pk = (unsigned int*)d_ws;        // 16*18432*4 B = 1.18 MiB

    hipMemsetAsync(out, 0, (size_t)out_size * sizeof(float), stream);  // capture-safe
    chanpack<<<dim3(NPAIR * RES), dim3(256), 0, stream>>>(x, w, pk);
    radon_k<<<dim3(NPAIR * 16 * 2), dim3(512), 0, stream>>>(pk, angles, bias, out);
}